// Round 1
// baseline (874.258 us; speedup 1.0000x reference)
//
#include <hip/hip_runtime.h>
#include <stdint.h>

// e4m3 fake quantize: out = sign(y) * min(round_rne_3bit_mantissa(|y|), 240) * s,
// y = x / s (IEEE division, bit-exact vs reference), subnormal grid (lsb = 2^-9)
// below 2^-6.
//
// Memory-bound elementwise. This version:
//  - persistent grid (2048 blocks = 8/CU), grid-stride loop
//  - 4 float4 loads in flight per thread per iteration (MLP=4) before compute
//  - nontemporal loads/stores (touch-once streams, 1 GiB total >> 256 MiB LLC)

typedef float f32x4 __attribute__((ext_vector_type(4)));

__device__ __forceinline__ float fq1(float x, float s) {
    // IEEE f32 division to match reference's x/s rounding exactly
    float y = x / s;
    uint32_t u  = __float_as_uint(y);
    uint32_t au = u & 0x7FFFFFFFu;          // |y| bits
    uint32_t sg = u & 0x80000000u;          // sign bit

    // Normal path: RNE-round mantissa to 3 bits (drop low 20 bits),
    // carry propagates into exponent correctly (e.g. 15.9 -> 16).
    uint32_t rn = au + (((au >> 20) & 1u) + 0x0007FFFFu);
    rn &= 0xFFF00000u;
    float qn = fminf(__uint_as_float(rn), 240.0f);

    // Subnormal path (|y| < 2^-6): fixed-point grid lsb = 2^-9.
    // Adding 2^14 places |y| so the f32 mantissa LSB is exactly 2^-9;
    // the add performs the RNE round, the subtract is exact.
    float ay = __uint_as_float(au);
    float qs = (ay + 16384.0f) - 16384.0f;

    float q = (au < 0x3C800000u) ? qs : qn; // 0x3C800000 = 2^-6

    // reapply sign, rescale
    q = __uint_as_float(__float_as_uint(q) | sg);
    return q * s;
}

__device__ __forceinline__ f32x4 fq4(f32x4 v, float s) {
    f32x4 r;
    r.x = fq1(v.x, s);
    r.y = fq1(v.y, s);
    r.z = fq1(v.z, s);
    r.w = fq1(v.w, s);
    return r;
}

__global__ __launch_bounds__(256) void fq_e4m3_kernel(
    const f32x4* __restrict__ x4,
    const float* __restrict__ scale,
    f32x4* __restrict__ out4,
    int n4)
{
    const float s = scale[0];               // uniform scalar load (s_load)
    const int stride = gridDim.x * blockDim.x;
    int i = blockIdx.x * blockDim.x + threadIdx.x;

    // Main loop: 4 independent float4 streams in flight per thread.
    for (; i + 3 * stride < n4; i += 4 * stride) {
        f32x4 a = __builtin_nontemporal_load(&x4[i]);
        f32x4 b = __builtin_nontemporal_load(&x4[i + stride]);
        f32x4 c = __builtin_nontemporal_load(&x4[i + 2 * stride]);
        f32x4 d = __builtin_nontemporal_load(&x4[i + 3 * stride]);

        a = fq4(a, s);
        b = fq4(b, s);
        c = fq4(c, s);
        d = fq4(d, s);

        __builtin_nontemporal_store(a, &out4[i]);
        __builtin_nontemporal_store(b, &out4[i + stride]);
        __builtin_nontemporal_store(c, &out4[i + 2 * stride]);
        __builtin_nontemporal_store(d, &out4[i + 3 * stride]);
    }
    // Tail (not hit at n4 = 2^25 with 2048x256 threads, kept for generality).
    for (; i < n4; i += stride) {
        f32x4 a = __builtin_nontemporal_load(&x4[i]);
        a = fq4(a, s);
        __builtin_nontemporal_store(a, &out4[i]);
    }
}

extern "C" void kernel_launch(void* const* d_in, const int* in_sizes, int n_in,
                              void* d_out, int out_size, void* d_ws, size_t ws_size,
                              hipStream_t stream) {
    const float* x     = (const float*)d_in[0];
    const float* scale = (const float*)d_in[1];
    float* out         = (float*)d_out;

    int n  = in_sizes[0];        // 8*4096*4096 = 134217728, divisible by 4
    int n4 = n >> 2;

    const int block = 256;
    int grid = (n4 + block - 1) / block;
    const int max_grid = 256 * 8;            // 8 persistent blocks per CU
    if (grid > max_grid) grid = max_grid;    // 2048 blocks, 64 float4/thread

    fq_e4m3_kernel<<<grid, block, 0, stream>>>(
        (const f32x4*)x, scale, (f32x4*)out, n4);
}

// Round 2
// 821.514 us; speedup vs baseline: 1.0642x; 1.0642x over previous
//
#include <hip/hip_runtime.h>
#include <stdint.h>

// e4m3 fake quantize: out = sign(y) * min(round_rne_3bit_mantissa(|y|), 240) * s,
// y = x / s (IEEE division, bit-exact vs reference), subnormal grid (lsb = 2^-9)
// below 2^-6.
//
// Memory-bound elementwise. Structure = round-0 block sweep (cached loads/stores,
// contiguous per-block footprint, block churn) + ONE change: each block owns two
// ADJACENT 4 KB tiles and each thread issues both float4 loads before any
// compute (MLP=2). No nontemporal, no persistent grid, no long-stride streams
// (those regressed 805 -> 874 in round 1).

typedef float f32x4 __attribute__((ext_vector_type(4)));

__device__ __forceinline__ float fq1(float x, float s) {
    // IEEE f32 division to match reference's x/s rounding exactly
    float y = x / s;
    uint32_t u  = __float_as_uint(y);
    uint32_t au = u & 0x7FFFFFFFu;          // |y| bits
    uint32_t sg = u & 0x80000000u;          // sign bit

    // Normal path: RNE-round mantissa to 3 bits (drop low 20 bits),
    // carry propagates into exponent correctly (e.g. 15.9 -> 16).
    uint32_t rn = au + (((au >> 20) & 1u) + 0x0007FFFFu);
    rn &= 0xFFF00000u;
    float qn = fminf(__uint_as_float(rn), 240.0f);

    // Subnormal path (|y| < 2^-6): fixed-point grid lsb = 2^-9.
    // Adding 2^14 places |y| so the f32 mantissa LSB is exactly 2^-9;
    // the add performs the RNE round, the subtract is exact.
    float ay = __uint_as_float(au);
    float qs = (ay + 16384.0f) - 16384.0f;

    float q = (au < 0x3C800000u) ? qs : qn; // 0x3C800000 = 2^-6

    // reapply sign, rescale
    q = __uint_as_float(__float_as_uint(q) | sg);
    return q * s;
}

__device__ __forceinline__ f32x4 fq4(f32x4 v, float s) {
    f32x4 r;
    r.x = fq1(v.x, s);
    r.y = fq1(v.y, s);
    r.z = fq1(v.z, s);
    r.w = fq1(v.w, s);
    return r;
}

__global__ __launch_bounds__(256) void fq_e4m3_kernel(
    const f32x4* __restrict__ x4,
    const float* __restrict__ scale,
    f32x4* __restrict__ out4,
    int n4)
{
    const float s = scale[0];               // uniform scalar load (L2-resident)

    // Block b covers float4 indices [b*512, b*512 + 512): two adjacent tiles.
    const int i0 = blockIdx.x * 512 + threadIdx.x;
    const int i1 = i0 + 256;

    if (i1 < n4) {
        // Both loads issued back-to-back before any dependent compute (MLP=2).
        f32x4 a = x4[i0];
        f32x4 b = x4[i1];
        a = fq4(a, s);
        b = fq4(b, s);
        out4[i0] = a;
        out4[i1] = b;
    } else if (i0 < n4) {
        f32x4 a = x4[i0];
        out4[i0] = fq4(a, s);
    }
}

extern "C" void kernel_launch(void* const* d_in, const int* in_sizes, int n_in,
                              void* d_out, int out_size, void* d_ws, size_t ws_size,
                              hipStream_t stream) {
    const float* x     = (const float*)d_in[0];
    const float* scale = (const float*)d_in[1];
    float* out         = (float*)d_out;

    int n  = in_sizes[0];        // 8*4096*4096 = 134217728, divisible by 4
    int n4 = n >> 2;             // 33554432 float4s, divisible by 512

    const int per_block = 512;   // 2 tiles x 256 threads
    int grid = (n4 + per_block - 1) / per_block;   // 65536 blocks

    fq_e4m3_kernel<<<grid, 256, 0, stream>>>(
        (const f32x4*)x, scale, (f32x4*)out, n4);
}